// Round 5
// baseline (200.550 us; speedup 1.0000x reference)
//
#include <hip/hip_runtime.h>

typedef __attribute__((ext_vector_type(8))) short bf16x8;
typedef __attribute__((ext_vector_type(8))) unsigned short u16x8;
typedef __attribute__((ext_vector_type(4))) float f32x4;

__device__ __forceinline__ unsigned short f2b(float x) {
    unsigned int u = __float_as_uint(x);
    u += 0x7FFFu + ((u >> 16) & 1u);
    return (unsigned short)(u >> 16);
}
__device__ __forceinline__ float b2f(unsigned short h) {
    return __uint_as_float(((unsigned int)h) << 16);
}
__device__ __forceinline__ float lrelu(float v) { return v >= 0.f ? v : 0.3f * v; }

// async global->LDS, 16B per lane, linear LDS dest (wave-uniform base + lane*16)
#define GLL(gp, lp) __builtin_amdgcn_global_load_lds( \
    (const __attribute__((address_space(1))) unsigned int*)(gp), \
    (__attribute__((address_space(3))) unsigned int*)(lp), 16, 0, 0)

// ---------------- workspace layout (bytes) ----------------
// QRAW   @ 0          : 33,554,432  (8*128*128*128 bf16)  -- dead after K3:
//   SIM  @ 0          : 2,097,152   (f32 [8][256][256])
//   ACTP @ 4194304    : 2,985,984   ([8][18][18][256] bf16, zero halo)
//   Y    @ 8388608    : 4,194,304   (f32 [8][32][32][128])
// KRAW   @ 33554432   : 33,554,432
// WQT    @ 67108864   : 294,912     ([9 tap][4 q][128 co][32 ci] bf16, chunk^=co&3)
// WKT    @ 67403776   : 294,912
// WTT    @ 67698688   : 1,048,576   ([16][co128][ci256] bf16)
// STATS  @ 68747264   : 8,192       (2048 f32)
// XB     @ 68761600   : 36,208,640  ([8][4 q][130 h][136 w][32] bf16, chunk^=w&3)
//   PART @ XB+0       : 33,554,432  (f32 [16 kc][8 b][256 f][256 q]) -- overlays dead Xb
// end 104,970,240  (< 105,469,952 proven footprint)

// K0a: zero stats, transpose+convert weights to bf16.
// Wq/Wk: [tap][ci][co] -> [tap][q4][co][4 chunk][8] with chunk ^= co&3
__global__ __launch_bounds__(256) void k0a_prep(
        const float* __restrict__ Wq, const float* __restrict__ Wk,
        const float* __restrict__ Wt, unsigned short* __restrict__ WqT,
        unsigned short* __restrict__ WkT, unsigned short* __restrict__ WtT,
        float* __restrict__ S) {
    int idx = blockIdx.x * 256 + threadIdx.x;
    int gs = gridDim.x * 256;
    for (int i = idx; i < 2048; i += gs) S[i] = 0.f;
    for (int i = idx; i < 147456; i += gs) {
        int tap = i >> 14, r = i & 16383, ci = r >> 7, co = r & 127;
        int q = ci >> 5, cl = (ci >> 3) & 3, e = ci & 7;
        int dst = (((tap * 4 + q) * 128 + co) * 4 + (cl ^ (co & 3))) * 8 + e;
        WqT[dst] = f2b(Wq[i]);
        WkT[dst] = f2b(Wk[i]);
    }
    for (int i = idx; i < 524288; i += gs) {      // [t][ci256][co128] -> [t][co][ci]
        int t = i >> 15, r = i & 32767, ci = r >> 7, co = r & 127;
        WtT[(((size_t)t << 7) + co) * 256 + ci] = f2b(Wt[i]);
    }
}

// K0b: pad+convert input to bf16 [b][q4][h130][w136][4 chunk][8], chunk^=w&3, zero halo/pad
__global__ __launch_bounds__(256) void k0b_padx(const float* __restrict__ X,
                                                unsigned short* __restrict__ Xb) {
    int c = blockIdx.x * 256 + threadIdx.x;       // < 2,263,040 chunks of 8
    if (c >= 2263040) return;
    int pc = c & 3;
    int t = c >> 2;
    int w = t % 136; t /= 136;
    int h = t % 130; t /= 130;
    int q = t & 3; int b = t >> 2;
    u16x8 o;
    if (h >= 1 && h <= 128 && w >= 1 && w <= 128) {
        int ci = q * 32 + ((pc ^ (w & 3)) << 3);
        const float* s = X + (((size_t)(b * 128 + h - 1) * 128) + (w - 1)) * 128 + ci;
        float4 f0 = *(const float4*)(s);
        float4 f1 = *(const float4*)(s + 4);
        o[0] = f2b(f0.x); o[1] = f2b(f0.y); o[2] = f2b(f0.z); o[3] = f2b(f0.w);
        o[4] = f2b(f1.x); o[5] = f2b(f1.y); o[6] = f2b(f1.z); o[7] = f2b(f1.w);
    } else {
#pragma unroll
        for (int j = 0; j < 8; ++j) o[j] = 0;
    }
    *(u16x8*)&Xb[(size_t)c * 8] = o;
}

// K1: 3x3 conv, one conv per block. M=256 (2 rows x 128 w), N=128 co, K=1152.
// 36 phases of K=32 (q-quarter x tap). BOTH rows and weights staged via
// global_load_lds into double-buffered LDS with counted vmcnt (never 0 mid-loop).
// LDS 52KB -> 2 blocks/CU.
__global__ __launch_bounds__(512, 4) void k1_conv(
        const unsigned short* __restrict__ Xb,
        const unsigned short* __restrict__ WqT, const unsigned short* __restrict__ WkT,
        unsigned short* __restrict__ Qraw, unsigned short* __restrict__ Kraw,
        float* __restrict__ S) {
    __shared__ unsigned short s_row[2][8704];   // [buf][2 r][136 w][32], 17408B each
    __shared__ unsigned short s_w[2][4096];     // [buf][128 co][32], 8192B each
    __shared__ float s_st[256];
    const int tid = threadIdx.x;
    const int x = blockIdx.x;
    const int conv = x & 1, hp = (x >> 1) & 63, b = x >> 7;
    const int h0 = hp * 2;
    const int lane = tid & 63, wv = tid >> 6;
    const int wm = wv & 3, wn = wv >> 2;        // 4 M-waves x 2 N-waves
    const int l15 = lane & 15;
    const int cl = lane >> 4;                   // logical chunk 0..3 (ci = cl*8)
    const int ar = wm >> 1;                     // output row within strip
    const int awb = (wm & 1) * 64;              // w base
    const int nb = wn * 64;                     // co base
    const unsigned short* W = conv ? WkT : WqT;
    const size_t xbb = (size_t)b * 2263040;     // elems per batch: 4*130*136*32

    f32x4 acc[4][4];
#pragma unroll
    for (int i = 0; i < 4; ++i)
#pragma unroll
        for (int j = 0; j < 4; ++j) acc[i][j] = (f32x4){0.f, 0.f, 0.f, 0.f};
    if (tid < 256) s_st[tid] = 0.f;

    // prologue: w(0) then rows(0)  (FIFO: weights oldest)
    {
        GLL((const char*)W + wv * 1024 + lane * 16, (char*)&s_w[0][0] + wv * 1024);
        const char* rsrc = (const char*)(Xb + xbb + (size_t)h0 * 4352);
        for (int u = wv; u < 17; u += 8)
            GLL(rsrc + u * 1024 + lane * 16, (char*)&s_row[0][0] + u * 1024);
    }

#pragma unroll
    for (int p = 0; p < 36; ++p) {
        const int s = p / 3, dx = p % 3;
        __builtin_amdgcn_s_barrier();           // (A) prior phase's reads done
        if (p < 35) {                            // issue w(p+1)
            const int pn = p + 1, ntap = pn % 9, nq = pn / 9;
            const char* wsrc = (const char*)(W + (size_t)(ntap * 4 + nq) * 4096);
            GLL(wsrc + wv * 1024 + lane * 16, (char*)&s_w[pn & 1][0] + wv * 1024);
        }
        if (dx == 0 && s < 11) {                 // issue rows(s+1)
            const int sn = s + 1, nq2 = sn / 3, ndy = sn % 3;
            const char* rsrc = (const char*)(Xb + xbb + (size_t)(nq2 * 130 + h0 + ndy) * 4352);
            char* rdst = (char*)&s_row[sn & 1][0];
            for (int u = wv; u < 17; u += 8)
                GLL(rsrc + u * 1024 + lane * 16, rdst + u * 1024);
        }
        // counted waits: need w(p) [and rows(s) by first phase of stage s]
        if (p == 35)                  asm volatile("s_waitcnt vmcnt(0)" ::: "memory");
        else if (dx == 2 || s == 11)  asm volatile("s_waitcnt vmcnt(1)" ::: "memory");
        else                          asm volatile("s_waitcnt vmcnt(3)" ::: "memory");
        __builtin_amdgcn_sched_barrier(0);
        __builtin_amdgcn_s_barrier();           // (B) staged data visible
        const unsigned short* wb = &s_w[p & 1][0];
        const unsigned short* rb = &s_row[s & 1][0];
        bf16x8 a[4], bb[4];
#pragma unroll
        for (int mf = 0; mf < 4; ++mf) {
            int wph = awb + mf * 16 + l15 + dx;
            a[mf] = *(const bf16x8*)&rb[(ar * 136 + wph) * 32 + ((cl ^ (wph & 3)) << 3)];
        }
#pragma unroll
        for (int nf = 0; nf < 4; ++nf) {
            int co = nb + nf * 16 + l15;
            bb[nf] = *(const bf16x8*)&wb[co * 32 + ((cl ^ (co & 3)) << 3)];
        }
        __builtin_amdgcn_s_setprio(1);
#pragma unroll
        for (int mf = 0; mf < 4; ++mf)
#pragma unroll
            for (int nf = 0; nf < 4; ++nf)
                acc[mf][nf] = __builtin_amdgcn_mfma_f32_16x16x32_bf16(
                    a[mf], bb[nf], acc[mf][nf], 0, 0, 0);
        __builtin_amdgcn_s_setprio(0);
    }
    __syncthreads();
    unsigned short* obase = conv ? Kraw : Qraw;
    const int h = h0 + ar;
    float sl[4] = {0.f, 0.f, 0.f, 0.f}, ssl[4] = {0.f, 0.f, 0.f, 0.f};
#pragma unroll
    for (int mf = 0; mf < 4; ++mf)
#pragma unroll
        for (int nf = 0; nf < 4; ++nf)
#pragma unroll
            for (int r = 0; r < 4; ++r) {
                float v = acc[mf][nf][r];
                int w = awb + mf * 16 + (lane >> 4) * 4 + r;
                int co = nb + nf * 16 + l15;
                obase[((size_t)(b * 128 + h) * 128 + w) * 128 + co] = f2b(v);
                sl[nf] += v; ssl[nf] += v * v;
            }
#pragma unroll
    for (int nf = 0; nf < 4; ++nf) {
        float s = sl[nf], ss = ssl[nf];
        s += __shfl_xor(s, 16); s += __shfl_xor(s, 32);
        ss += __shfl_xor(ss, 16); ss += __shfl_xor(ss, 32);
        if (lane < 16) {
            int chn = nb + nf * 16 + lane;
            atomicAdd(&s_st[chn], s);
            atomicAdd(&s_st[128 + chn], ss);
        }
    }
    __syncthreads();
    if (tid < 256) {
        int dst = (tid < 128) ? (conv * 128 + tid) : (256 + conv * 128 + (tid - 128));
        atomicAdd(&S[dst], s_st[tid]);
    }
}

// K3: sim partial GEMM, BN params computed in-block from S, BN+leaky in staging.
// grid = b(8) x mi(2) x ni(2) x kc(16). 128x128 tile, K=512 (4 windows)
__global__ __launch_bounds__(512, 2) void k3_sim(const unsigned short* __restrict__ Qp,
                                                 const unsigned short* __restrict__ Kp,
                                                 const float* __restrict__ S,
                                                 const float* __restrict__ gq, const float* __restrict__ bq,
                                                 const float* __restrict__ gk, const float* __restrict__ bk,
                                                 float* __restrict__ part) {
    __shared__ unsigned short sA[128 * 136];
    __shared__ unsigned short sB[128 * 136];
    __shared__ float s_p[512];
    const int tid = threadIdx.x;
    const int x = blockIdx.x;
    const int kc = x & 15, ni = (x >> 4) & 1, mi = (x >> 5) & 1, b = x >> 6;
    const int lane = tid & 63, wv = tid >> 6;
    const int wm = wv & 1, wn = wv >> 1;  // wave: 64(M) x 32(N)
    if (tid < 256) {
        const float inv_n = 1.f / 131072.f;
        float mean = S[tid] * inv_n;
        float var = S[256 + tid] * inv_n - mean * mean;
        float g  = (tid < 128) ? gq[tid] : gk[tid - 128];
        float be = (tid < 128) ? bq[tid] : bk[tid - 128];
        float sc = g * rsqrtf(var + 1e-3f);
        s_p[tid] = sc;
        s_p[256 + tid] = be - mean * sc;
    }
    f32x4 acc[4][2];
#pragma unroll
    for (int i = 0; i < 4; ++i)
#pragma unroll
        for (int j = 0; j < 2; ++j) acc[i][j] = (f32x4){0.f, 0.f, 0.f, 0.f};
    const int kof = (lane >> 4) * 8;
    const int arow = wm * 64 + (lane & 15);
    const int brow = wn * 32 + (lane & 15);

    for (int s = 0; s < 4; ++s) {
        const int p = kc * 4 + s, py = p >> 3, px = p & 7;
        __syncthreads();
        for (int c = tid; c < 2048; c += 512) {
            int r = c >> 4, k8 = c & 15;
            int cb = k8 * 8;
            int f = mi * 128 + r;
            size_t sa = ((size_t)(b * 128 + ((f >> 4) * 8 + py)) * 128 + ((f & 15) * 8 + px)) * 128 + cb;
            int q = ni * 128 + r;
            size_t sb = ((size_t)(b * 128 + ((q >> 4) * 8 + py)) * 128 + ((q & 15) * 8 + px)) * 128 + cb;
            u16x8 va = *(const u16x8*)&Kp[sa];
            u16x8 vb = *(const u16x8*)&Qp[sb];
            u16x8 oa, ob;
#pragma unroll
            for (int j = 0; j < 8; ++j) {
                float fk = b2f(va[j]);
                fk = lrelu(s_p[128 + cb + j] * fk + s_p[384 + cb + j]);
                oa[j] = f2b(fk);
                float fq = b2f(vb[j]);
                fq = lrelu(s_p[cb + j] * fq + s_p[256 + cb + j]);
                ob[j] = f2b(fq);
            }
            *(u16x8*)&sA[r * 136 + cb] = oa;
            *(u16x8*)&sB[r * 136 + cb] = ob;
        }
        __syncthreads();
#pragma unroll
        for (int k4 = 0; k4 < 4; ++k4) {
            const int ci = k4 * 32 + kof;
            bf16x8 a[4], bb[2];
#pragma unroll
            for (int mf = 0; mf < 4; ++mf)
                a[mf] = *(const bf16x8*)&sA[(arow + mf * 16) * 136 + ci];
#pragma unroll
            for (int nf = 0; nf < 2; ++nf)
                bb[nf] = *(const bf16x8*)&sB[(brow + nf * 16) * 136 + ci];
#pragma unroll
            for (int mf = 0; mf < 4; ++mf)
#pragma unroll
                for (int nf = 0; nf < 2; ++nf)
                    acc[mf][nf] = __builtin_amdgcn_mfma_f32_16x16x32_bf16(
                        a[mf], bb[nf], acc[mf][nf], 0, 0, 0);
        }
    }
    const size_t base = (size_t)(kc * 8 + b) * 65536;
#pragma unroll
    for (int mf = 0; mf < 4; ++mf)
#pragma unroll
        for (int nf = 0; nf < 2; ++nf)
#pragma unroll
            for (int r = 0; r < 4; ++r) {
                int f = mi * 128 + wm * 64 + mf * 16 + (lane >> 4) * 4 + r;
                int q = ni * 128 + wn * 32 + nf * 16 + (lane & 15);
                part[base + (size_t)f * 256 + q] = acc[mf][nf][r];
            }
}

// K4: reduce 16 K-chunks + beta bias -> sim; window-BN partial stats
__global__ __launch_bounds__(256) void k4_red(const float* __restrict__ part,
                                              const float* __restrict__ beta,
                                              float* __restrict__ sim, float* __restrict__ S) {
    int row0 = blockIdx.x * 8;
    int q = threadIdx.x;
    float bsum = 0.f, bss = 0.f;
    float bb = beta[q];
    for (int rr = 0; rr < 8; ++rr) {
        int row = row0 + rr;
        float s = 0.f;
#pragma unroll
        for (int kcc = 0; kcc < 16; ++kcc)
            s += part[(size_t)kcc * 524288 + (size_t)row * 256 + q];
        s += bb;
        sim[(size_t)row * 256 + q] = s;
        bsum += s; bss += s * s;
    }
    atomicAdd(&S[512 + q], bsum);
    atomicAdd(&S[768 + q], bss);
}

// K5b: act = leaky(BN(sim)) -> padded bf16 [8][18][18][256], params in-block
__global__ __launch_bounds__(256) void k5b_act(const float* __restrict__ sim,
                                               const float* __restrict__ S,
                                               const float* __restrict__ g1, const float* __restrict__ b1,
                                               unsigned short* __restrict__ actp) {
    __shared__ float s_p[512];
    {
        int c = threadIdx.x;  // 256
        const float inv_n = 1.f / 2048.f;
        float mean = S[512 + c] * inv_n;
        float var = S[768 + c] * inv_n - mean * mean;
        float sc = g1[c] * rsqrtf(var + 1e-3f);
        s_p[c] = sc;
        s_p[256 + c] = b1[c] - mean * sc;
    }
    __syncthreads();
    int c = blockIdx.x * 256 + threadIdx.x;  // < 186,624
    if (c >= 186624) return;
    int k8 = c & 31;
    int t = c >> 5;
    int jp = t % 18; t /= 18;
    int ip = t % 18; int b = t / 18;
    u16x8 o;
    if (ip >= 1 && ip <= 16 && jp >= 1 && jp <= 16) {
        int f = (ip - 1) * 16 + (jp - 1);
        const float* s = sim + (size_t)(b * 256 + f) * 256 + k8 * 8;
#pragma unroll
        for (int j = 0; j < 8; ++j) {
            int ci = k8 * 8 + j;
            o[j] = f2b(lrelu(s_p[ci] * s[j] + s_p[256 + ci]));
        }
    } else {
#pragma unroll
        for (int j = 0; j < 8; ++j) o[j] = 0;
    }
    *(u16x8*)&actp[(size_t)c * 8] = o;
}

// K6: conv-transpose by output parity. grid = b(8) x ph(2) x pw(2) x iq(4). M=64 N=128 K=1024
__global__ __launch_bounds__(512, 2) void k6_tconv(const unsigned short* __restrict__ actp,
                                                   const unsigned short* __restrict__ WtT,
                                                   float* __restrict__ y, float* __restrict__ S) {
    __shared__ unsigned short sA[64 * 264];
    __shared__ unsigned short sB[128 * 264];
    const int tid = threadIdx.x;
    const int x = blockIdx.x;
    const int iq = x & 3, pw = (x >> 2) & 1, ph = (x >> 3) & 1, b = x >> 4;
    const int lane = tid & 63, wv = tid >> 6;  // wave = one 16-wide co strip
    f32x4 acc[4];
#pragma unroll
    for (int i = 0; i < 4; ++i) acc[i] = (f32x4){0.f, 0.f, 0.f, 0.f};
    const int kof = (lane >> 4) * 8;
    const int arow = lane & 15;
    const int bco = wv * 16 + (lane & 15);

    for (int a2 = 0; a2 < 2; ++a2)
        for (int c2 = 0; c2 < 2; ++c2) {
            const int kh = ph + 2 * a2, kw = pw + 2 * c2;
            __syncthreads();
            for (int c = tid; c < 2048; c += 512) {   // A: 64 rows x 32 chunks
                int r = c >> 5, k8 = c & 31;
                int i = iq * 4 + (r >> 4), j = r & 15;
                size_t sa = (size_t)((b * 18 + (i + a2 + ph)) * 18 + (j + c2 + pw)) * 256 + k8 * 8;
                *(u16x8*)&sA[r * 264 + k8 * 8] = *(const u16x8*)&actp[sa];
            }
            for (int c = tid; c < 4096; c += 512) {   // B: 128 co x 32 chunks
                int co = c >> 5, k8 = c & 31;
                size_t sb = (size_t)((kh * 4 + kw) * 128 + co) * 256 + k8 * 8;
                *(u16x8*)&sB[co * 264 + k8 * 8] = *(const u16x8*)&WtT[sb];
            }
            __syncthreads();
#pragma unroll
            for (int k8c = 0; k8c < 8; ++k8c) {
                const int ci = k8c * 32 + kof;
                bf16x8 bb = *(const bf16x8*)&sB[bco * 264 + ci];
#pragma unroll
                for (int mf = 0; mf < 4; ++mf) {
                    bf16x8 a = *(const bf16x8*)&sA[(arow + mf * 16) * 264 + ci];
                    acc[mf] = __builtin_amdgcn_mfma_f32_16x16x32_bf16(a, bb, acc[mf], 0, 0, 0);
                }
            }
        }
    float sl = 0.f, ssl = 0.f;
#pragma unroll
    for (int mf = 0; mf < 4; ++mf)
#pragma unroll
        for (int r = 0; r < 4; ++r) {
            float v = acc[mf][r];
            int m = mf * 16 + (lane >> 4) * 4 + r;  // 0..63
            int i = iq * 4 + (m >> 4), j = m & 15;
            int oh = 2 * i + ph, ow = 2 * j + pw;
            y[(size_t)((b * 32 + oh) * 32 + ow) * 128 + bco] = v;
            sl += v; ssl += v * v;
        }
    sl += __shfl_xor(sl, 16); sl += __shfl_xor(sl, 32);
    ssl += __shfl_xor(ssl, 16); ssl += __shfl_xor(ssl, 32);
    if (lane < 16) {
        atomicAdd(&S[1024 + wv * 16 + lane], sl);
        atomicAdd(&S[1152 + wv * 16 + lane], ssl);
    }
}

// K8: out = leaky(BN(y)), f32, params in-block
__global__ __launch_bounds__(256) void k8_out(const float* __restrict__ y,
                                              const float* __restrict__ S,
                                              const float* __restrict__ gt, const float* __restrict__ bt,
                                              float* __restrict__ out) {
    __shared__ float s_p[256];
    if (threadIdx.x < 128) {
        int c = threadIdx.x;
        const float inv_n = 1.f / 8192.f;
        float mean = S[1024 + c] * inv_n;
        float var = S[1152 + c] * inv_n - mean * mean;
        float sc = gt[c] * rsqrtf(var + 1e-3f);
        s_p[c] = sc;
        s_p[128 + c] = bt[c] - mean * sc;
    }
    __syncthreads();
    int c = blockIdx.x * 256 + threadIdx.x;  // < 262,144
    const float4 v = *(const float4*)&y[(size_t)c * 4];
    int cb = (c & 31) * 4;
    float4 o;
    o.x = lrelu(s_p[cb + 0] * v.x + s_p[128 + cb + 0]);
    o.y = lrelu(s_p[cb + 1] * v.y + s_p[128 + cb + 1]);
    o.z = lrelu(s_p[cb + 2] * v.z + s_p[128 + cb + 2]);
    o.w = lrelu(s_p[cb + 3] * v.w + s_p[128 + cb + 3]);
    *(float4*)&out[(size_t)c * 4] = o;
}

extern "C" void kernel_launch(void* const* d_in, const int* in_sizes, int n_in,
                              void* d_out, int out_size, void* d_ws, size_t ws_size,
                              hipStream_t stream) {
    (void)in_sizes; (void)n_in; (void)out_size; (void)ws_size;
    const float* X    = (const float*)d_in[0];
    const float* Wq   = (const float*)d_in[1];
    const float* gq   = (const float*)d_in[2];
    const float* bq   = (const float*)d_in[3];
    const float* Wk   = (const float*)d_in[4];
    const float* gk   = (const float*)d_in[5];
    const float* bk   = (const float*)d_in[6];
    const float* beta = (const float*)d_in[7];
    const float* g1   = (const float*)d_in[8];
    const float* b1   = (const float*)d_in[9];
    const float* Wt   = (const float*)d_in[10];
    const float* gt   = (const float*)d_in[11];
    const float* bt   = (const float*)d_in[12];

    char* ws = (char*)d_ws;
    unsigned short* Qraw = (unsigned short*)(ws + 0ull);
    unsigned short* Kraw = (unsigned short*)(ws + 33554432ull);
    unsigned short* WqT  = (unsigned short*)(ws + 67108864ull);
    unsigned short* WkT  = (unsigned short*)(ws + 67403776ull);
    unsigned short* WtT  = (unsigned short*)(ws + 67698688ull);
    float* S             = (float*)(ws + 68747264ull);
    unsigned short* Xb   = (unsigned short*)(ws + 68761600ull);
    float* part          = (float*)(ws + 68761600ull);   // overlays dead Xb
    float* sim           = (float*)(ws + 0ull);          // overlays dead Qraw
    unsigned short* actp = (unsigned short*)(ws + 4194304ull);
    float* y             = (float*)(ws + 8388608ull);
    float* out           = (float*)d_out;

    k0a_prep<<<1024, 256, 0, stream>>>(Wq, Wk, Wt, WqT, WkT, WtT, S);
    k0b_padx<<<8840, 256, 0, stream>>>(X, Xb);
    k1_conv<<<1024, 512, 0, stream>>>(Xb, WqT, WkT, Qraw, Kraw, S);
    k3_sim<<<512, 512, 0, stream>>>(Qraw, Kraw, S, gq, bq, gk, bk, part);
    k4_red<<<256, 256, 0, stream>>>(part, beta, sim, S);
    k5b_act<<<729, 256, 0, stream>>>(sim, S, g1, b1, actp);
    k6_tconv<<<128, 512, 0, stream>>>(actp, WtT, y, S);
    k8_out<<<1024, 256, 0, stream>>>(y, S, gt, bt, out);
}

// Round 6
// 170.381 us; speedup vs baseline: 1.1771x; 1.1771x over previous
//
#include <hip/hip_runtime.h>

typedef __attribute__((ext_vector_type(8))) short bf16x8;
typedef __attribute__((ext_vector_type(8))) unsigned short u16x8;
typedef __attribute__((ext_vector_type(4))) float f32x4;

__device__ __forceinline__ unsigned short f2b(float x) {
    unsigned int u = __float_as_uint(x);
    u += 0x7FFFu + ((u >> 16) & 1u);
    return (unsigned short)(u >> 16);
}
__device__ __forceinline__ float b2f(unsigned short h) {
    return __uint_as_float(((unsigned int)h) << 16);
}
__device__ __forceinline__ float lrelu(float v) { return v >= 0.f ? v : 0.3f * v; }

// async global->LDS, 16B per lane, linear LDS dest (wave-uniform base + lane*16)
#define GLL(gp, lp) __builtin_amdgcn_global_load_lds( \
    (const __attribute__((address_space(1))) unsigned int*)(gp), \
    (__attribute__((address_space(3))) unsigned int*)(lp), 16, 0, 0)

// ---------------- workspace layout (bytes) ----------------
// QRAW   @ 0          : 33,554,432  (8*128*128*128 bf16)  -- dead after K3:
//   SIM  @ 0          : 2,097,152   (f32 [8][256][256])
//   ACTP @ 4194304    : 2,985,984   ([8][18][18][256] bf16, zero halo)
//   Y    @ 8388608    : 4,194,304   (f32 [8][32][32][128])
// KRAW   @ 33554432   : 33,554,432
// WQT    @ 67108864   : 294,912     ([9 tap][2 ch][128 co][64 ci] bf16, chunk^=co&7)
// WKT    @ 67403776   : 294,912
// WTT    @ 67698688   : 1,048,576   ([16][co128][ci256] bf16)
// STATS  @ 68747264   : 8,192       (2048 f32)
// XB     @ 68761600   : 34,611,200  ([8][130 h][2 ch][130 w][64] bf16)  -- dead after K1:
//   PART @ XB+0       : 16,777,216  (f32 [8 kc][8 b][256 f][256 q])

// K0a: zero stats, transpose+convert weights to bf16.
// Wq/Wk: [tap][ci][co] -> [tap][ch][co][64] with 16B-chunk XOR swizzle (chunk ^= co&7)
__global__ __launch_bounds__(256) void k0a_prep(
        const float* __restrict__ Wq, const float* __restrict__ Wk,
        const float* __restrict__ Wt, unsigned short* __restrict__ WqT,
        unsigned short* __restrict__ WkT, unsigned short* __restrict__ WtT,
        float* __restrict__ S) {
    int idx = blockIdx.x * 256 + threadIdx.x;
    int gs = gridDim.x * 256;
    for (int i = idx; i < 2048; i += gs) S[i] = 0.f;
    for (int i = idx; i < 147456; i += gs) {
        int tap = i >> 14, r = i & 16383, ci = r >> 7, co = r & 127;
        int ch = ci >> 6, e = ci & 63;
        int dst = ((tap * 2 + ch) * 128 + co) * 64 + (((e >> 3) ^ (co & 7)) << 3) + (e & 7);
        WqT[dst] = f2b(Wq[i]);
        WkT[dst] = f2b(Wk[i]);
    }
    for (int i = idx; i < 524288; i += gs) {      // [t][ci256][co128] -> [t][co][ci]
        int t = i >> 15, r = i & 32767, ci = r >> 7, co = r & 127;
        WtT[(((size_t)t << 7) + co) * 256 + ci] = f2b(Wt[i]);
    }
}

// K0b: pad+convert input to bf16 [b][130][2 ch][130][64], zero halo
__global__ __launch_bounds__(256) void k0b_padx(const float* __restrict__ X,
                                                unsigned short* __restrict__ Xb) {
    int c = blockIdx.x * 256 + threadIdx.x;       // < 2,163,200 chunks of 8
    int k8 = c & 7;
    int t = c >> 3;
    int wp = t % 130; t /= 130;
    int ch = t & 1; t >>= 1;
    int hp = t % 130; int b = t / 130;
    u16x8 o;
    if (hp >= 1 && hp <= 128 && wp >= 1 && wp <= 128) {
        const float* s = X + (((size_t)(b * 128 + hp - 1) * 128) + (wp - 1)) * 128 + ch * 64 + k8 * 8;
        float4 f0 = *(const float4*)(s);
        float4 f1 = *(const float4*)(s + 4);
        o[0] = f2b(f0.x); o[1] = f2b(f0.y); o[2] = f2b(f0.z); o[3] = f2b(f0.w);
        o[4] = f2b(f1.x); o[5] = f2b(f1.y); o[6] = f2b(f1.z); o[7] = f2b(f1.w);
    } else {
#pragma unroll
        for (int j = 0; j < 8; ++j) o[j] = 0;
    }
    *(u16x8*)&Xb[(size_t)c * 8] = o;
}

// K1: 3x3 conv, one conv per block. M=256 (2 rows x 128 w), N=128 co, K=1152.
// 512 thr = 8 waves (4M x 2N), 64x64 wave tiles. Weights async via global_load_lds
// into double-buffered s_w (counted vmcnt, raw barriers; 2 GLL/wave/stage uniform).
// XCD-aware block remap: conv-pair + hp-neighbors share an XCD L2.
// LDS 71.2KB -> 2 blocks/CU.
__global__ __launch_bounds__(512, 4) void k1_conv(
        const unsigned short* __restrict__ Xb,
        const unsigned short* __restrict__ WqT, const unsigned short* __restrict__ WkT,
        unsigned short* __restrict__ Qraw, unsigned short* __restrict__ Kraw,
        float* __restrict__ S) {
    __shared__ unsigned short s_row[2 * 130 * 72];   // [r2][w130][ci-half pad72]
    __shared__ unsigned short s_w[2][128 * 64];      // dbuf [co][64], chunk-swizzled
    __shared__ float s_st[256];
    const int tid = threadIdx.x;
    // XCD-aware decode: xcd = x&7 keeps conv pairs + hp range on one XCD
    const int x = blockIdx.x;
    const int xcd = x & 7, sdec = x >> 3;            // sdec 0..127
    const int b = sdec >> 4, r16 = sdec & 15;
    const int hp = xcd * 8 + (r16 >> 1), conv = r16 & 1;
    const int h0 = hp * 2;
    const int lane = tid & 63, wv = tid >> 6;
    const int wm = wv & 3, wn = wv >> 2;             // 4 M-waves x 2 N-waves
    const int l15 = lane & 15, kof = (lane >> 4) * 8;
    const int ar = wm >> 1;                          // output row within strip
    const int awb = (wm & 1) * 64;                   // w base
    const int nb = wn * 64;                          // co base

    const unsigned short* W = conv ? WkT : WqT;      // pre-swizzled [tap][ch][co][64]
    const int gofs = wv * 2048 + lane * 16;          // per-lane byte offset in a stage

    f32x4 acc[4][4];
#pragma unroll
    for (int i = 0; i < 4; ++i)
#pragma unroll
        for (int j = 0; j < 4; ++j) acc[i][j] = (f32x4){0.f, 0.f, 0.f, 0.f};
    if (tid < 256) s_st[tid] = 0.f;

    // prologue: stage W(ch0, tap0) -> s_w[0]  (2 GLLs per wave, uniform)
    {
        const char* src = (const char*)W;
        char* dst = (char*)&s_w[0][0] + wv * 2048;
        GLL(src + gofs, dst);
        GLL(src + gofs + 1024, dst + 1024);
    }

#pragma unroll
    for (int ch = 0; ch < 2; ++ch) {
#pragma unroll
        for (int dy = 0; dy < 3; ++dy) {
#pragma unroll
            for (int dx = 0; dx < 3; ++dx) {
                const int p = (ch * 3 + dy) * 3 + dx;   // 0..17
                __builtin_amdgcn_s_barrier();           // (A) prior reads done
                if (dx == 0) {
                    // stage rows (ch,dy): 2 rows x 130 w x 64 ci-half, padded 72
                    const unsigned short* src0 = Xb + (size_t)((b * 130 + h0 + dy) * 2 + ch) * 8320;
                    const unsigned short* src1 = Xb + (size_t)((b * 130 + h0 + dy + 1) * 2 + ch) * 8320;
                    for (int c = tid; c < 2080; c += 512) {
                        int r = (c >= 1040);
                        int cw = r ? c - 1040 : c;      // w*8 + k8
                        int w = cw >> 3, k8 = cw & 7;
                        *(u16x8*)&s_row[(r * 130 + w) * 72 + k8 * 8] =
                            *(const u16x8*)&((r ? src1 : src0)[cw * 8]);
                    }
                }
                if (p < 17) {
                    const int pn = p + 1;
                    const int nch = pn / 9, ntap = pn % 9;
                    const char* src = (const char*)(W + ((size_t)(ntap * 2 + nch) << 13));
                    char* dst = (char*)&s_w[pn & 1][0] + wv * 2048;
                    GLL(src + gofs, dst);
                    GLL(src + gofs + 1024, dst + 1024);
                    asm volatile("s_waitcnt vmcnt(2) lgkmcnt(0)" ::: "memory");
                } else {
                    asm volatile("s_waitcnt vmcnt(0) lgkmcnt(0)" ::: "memory");
                }
                __builtin_amdgcn_sched_barrier(0);
                __builtin_amdgcn_s_barrier();           // (B) s_w[p&1] + rows visible
                const unsigned short* wb = &s_w[p & 1][0];
#pragma unroll
                for (int kc = 0; kc < 2; ++kc) {
                    const int ci = kc * 32 + kof;       // 0..63 within ci-half
                    bf16x8 a[4], bb[4];
#pragma unroll
                    for (int mf = 0; mf < 4; ++mf)
                        a[mf] = *(const bf16x8*)&s_row[(ar * 130 + awb + mf * 16 + l15 + dx) * 72 + ci];
#pragma unroll
                    for (int nf = 0; nf < 4; ++nf) {
                        int co = nb + nf * 16 + l15;
                        bb[nf] = *(const bf16x8*)&wb[co * 64 + (((ci >> 3) ^ (co & 7)) << 3)];
                    }
#pragma unroll
                    for (int mf = 0; mf < 4; ++mf)
#pragma unroll
                        for (int nf = 0; nf < 4; ++nf)
                            acc[mf][nf] = __builtin_amdgcn_mfma_f32_16x16x32_bf16(
                                a[mf], bb[nf], acc[mf][nf], 0, 0, 0);
                }
            }
        }
    }
    __syncthreads();
    unsigned short* obase = conv ? Kraw : Qraw;
    const int h = h0 + ar;
    float sl[4] = {0.f, 0.f, 0.f, 0.f}, ssl[4] = {0.f, 0.f, 0.f, 0.f};
#pragma unroll
    for (int mf = 0; mf < 4; ++mf)
#pragma unroll
        for (int nf = 0; nf < 4; ++nf)
#pragma unroll
            for (int r = 0; r < 4; ++r) {
                float v = acc[mf][nf][r];
                int w = awb + mf * 16 + (lane >> 4) * 4 + r;
                int co = nb + nf * 16 + l15;
                obase[((size_t)(b * 128 + h) * 128 + w) * 128 + co] = f2b(v);
                sl[nf] += v; ssl[nf] += v * v;
            }
#pragma unroll
    for (int nf = 0; nf < 4; ++nf) {
        float s = sl[nf], ss = ssl[nf];
        s += __shfl_xor(s, 16); s += __shfl_xor(s, 32);
        ss += __shfl_xor(ss, 16); ss += __shfl_xor(ss, 32);
        if (lane < 16) {
            int chn = nb + nf * 16 + lane;           // 0..127 within this conv
            atomicAdd(&s_st[chn], s);
            atomicAdd(&s_st[128 + chn], ss);
        }
    }
    __syncthreads();
    if (tid < 256) {
        int dst = (tid < 128) ? (conv * 128 + tid) : (256 + conv * 128 + (tid - 128));
        atomicAdd(&S[dst], s_st[tid]);
    }
}

// K3: sim partial GEMM, BN params computed in-block from S, BN+leaky in staging.
// grid 256, XCD-decoded: kc = xcd (8 K-chunks of K=1024), 4 (mi,ni) tiles of a
// (b,kc) group co-located per XCD. 128x128 tile, 8 windows (one py row).
__global__ __launch_bounds__(512, 2) void k3_sim(const unsigned short* __restrict__ Qp,
                                                 const unsigned short* __restrict__ Kp,
                                                 const float* __restrict__ S,
                                                 const float* __restrict__ gq, const float* __restrict__ bq,
                                                 const float* __restrict__ gk, const float* __restrict__ bk,
                                                 float* __restrict__ part) {
    __shared__ unsigned short sA[128 * 136];
    __shared__ unsigned short sB[128 * 136];
    __shared__ float s_p[512];
    const int tid = threadIdx.x;
    const int x = blockIdx.x;
    const int kc = x & 7, sdec = x >> 3;            // kc = xcd
    const int b = sdec >> 2, mn = sdec & 3;
    const int mi = mn >> 1, ni = mn & 1;
    const int lane = tid & 63, wv = tid >> 6;
    const int wm = wv & 1, wn = wv >> 1;  // wave: 64(M) x 32(N)
    if (tid < 256) {
        const float inv_n = 1.f / 131072.f;
        float mean = S[tid] * inv_n;
        float var = S[256 + tid] * inv_n - mean * mean;
        float g  = (tid < 128) ? gq[tid] : gk[tid - 128];
        float be = (tid < 128) ? bq[tid] : bk[tid - 128];
        float sc = g * rsqrtf(var + 1e-3f);
        s_p[tid] = sc;
        s_p[256 + tid] = be - mean * sc;
    }
    f32x4 acc[4][2];
#pragma unroll
    for (int i = 0; i < 4; ++i)
#pragma unroll
        for (int j = 0; j < 2; ++j) acc[i][j] = (f32x4){0.f, 0.f, 0.f, 0.f};
    const int kof = (lane >> 4) * 8;
    const int arow = wm * 64 + (lane & 15);
    const int brow = wn * 32 + (lane & 15);

    for (int s = 0; s < 8; ++s) {
        const int py = kc, px = s;                  // window p = kc*8+s
        __syncthreads();
        for (int c = tid; c < 2048; c += 512) {
            int r = c >> 4, k8 = c & 15;
            int cb = k8 * 8;
            int f = mi * 128 + r;
            size_t sa = ((size_t)(b * 128 + ((f >> 4) * 8 + py)) * 128 + ((f & 15) * 8 + px)) * 128 + cb;
            int q = ni * 128 + r;
            size_t sb = ((size_t)(b * 128 + ((q >> 4) * 8 + py)) * 128 + ((q & 15) * 8 + px)) * 128 + cb;
            u16x8 va = *(const u16x8*)&Kp[sa];
            u16x8 vb = *(const u16x8*)&Qp[sb];
            u16x8 oa, ob;
#pragma unroll
            for (int j = 0; j < 8; ++j) {
                float fk = b2f(va[j]);
                fk = lrelu(s_p[128 + cb + j] * fk + s_p[384 + cb + j]);
                oa[j] = f2b(fk);
                float fq = b2f(vb[j]);
                fq = lrelu(s_p[cb + j] * fq + s_p[256 + cb + j]);
                ob[j] = f2b(fq);
            }
            *(u16x8*)&sA[r * 136 + cb] = oa;
            *(u16x8*)&sB[r * 136 + cb] = ob;
        }
        __syncthreads();
#pragma unroll
        for (int k4 = 0; k4 < 4; ++k4) {
            const int ci = k4 * 32 + kof;
            bf16x8 a[4], bb[2];
#pragma unroll
            for (int mf = 0; mf < 4; ++mf)
                a[mf] = *(const bf16x8*)&sA[(arow + mf * 16) * 136 + ci];
#pragma unroll
            for (int nf = 0; nf < 2; ++nf)
                bb[nf] = *(const bf16x8*)&sB[(brow + nf * 16) * 136 + ci];
#pragma unroll
            for (int mf = 0; mf < 4; ++mf)
#pragma unroll
                for (int nf = 0; nf < 2; ++nf)
                    acc[mf][nf] = __builtin_amdgcn_mfma_f32_16x16x32_bf16(
                        a[mf], bb[nf], acc[mf][nf], 0, 0, 0);
        }
    }
    const size_t base = (size_t)(kc * 8 + b) * 65536;
#pragma unroll
    for (int mf = 0; mf < 4; ++mf)
#pragma unroll
        for (int nf = 0; nf < 2; ++nf)
#pragma unroll
            for (int r = 0; r < 4; ++r) {
                int f = mi * 128 + wm * 64 + mf * 16 + (lane >> 4) * 4 + r;
                int q = ni * 128 + wn * 32 + nf * 16 + (lane & 15);
                part[base + (size_t)f * 256 + q] = acc[mf][nf][r];
            }
}

// K4: reduce 8 K-chunks + beta bias -> sim; window-BN partial stats
__global__ __launch_bounds__(256) void k4_red(const float* __restrict__ part,
                                              const float* __restrict__ beta,
                                              float* __restrict__ sim, float* __restrict__ S) {
    int row0 = blockIdx.x * 8;
    int q = threadIdx.x;
    float bsum = 0.f, bss = 0.f;
    float bb = beta[q];
    for (int rr = 0; rr < 8; ++rr) {
        int row = row0 + rr;
        float s = 0.f;
#pragma unroll
        for (int kcc = 0; kcc < 8; ++kcc)
            s += part[(size_t)kcc * 524288 + (size_t)row * 256 + q];
        s += bb;
        sim[(size_t)row * 256 + q] = s;
        bsum += s; bss += s * s;
    }
    atomicAdd(&S[512 + q], bsum);
    atomicAdd(&S[768 + q], bss);
}

// K5b: act = leaky(BN(sim)) -> padded bf16 [8][18][18][256], params in-block
__global__ __launch_bounds__(256) void k5b_act(const float* __restrict__ sim,
                                               const float* __restrict__ S,
                                               const float* __restrict__ g1, const float* __restrict__ b1,
                                               unsigned short* __restrict__ actp) {
    __shared__ float s_p[512];
    {
        int c = threadIdx.x;  // 256
        const float inv_n = 1.f / 2048.f;
        float mean = S[512 + c] * inv_n;
        float var = S[768 + c] * inv_n - mean * mean;
        float sc = g1[c] * rsqrtf(var + 1e-3f);
        s_p[c] = sc;
        s_p[256 + c] = b1[c] - mean * sc;
    }
    __syncthreads();
    int c = blockIdx.x * 256 + threadIdx.x;  // < 186,624
    if (c >= 186624) return;
    int k8 = c & 31;
    int t = c >> 5;
    int jp = t % 18; t /= 18;
    int ip = t % 18; int b = t / 18;
    u16x8 o;
    if (ip >= 1 && ip <= 16 && jp >= 1 && jp <= 16) {
        int f = (ip - 1) * 16 + (jp - 1);
        const float* s = sim + (size_t)(b * 256 + f) * 256 + k8 * 8;
#pragma unroll
        for (int j = 0; j < 8; ++j) {
            int ci = k8 * 8 + j;
            o[j] = f2b(lrelu(s_p[ci] * s[j] + s_p[256 + ci]));
        }
    } else {
#pragma unroll
        for (int j = 0; j < 8; ++j) o[j] = 0;
    }
    *(u16x8*)&actp[(size_t)c * 8] = o;
}

// K6: conv-transpose by output parity. grid = b(8) x ph(2) x pw(2) x iq(4). M=64 N=128 K=1024
__global__ __launch_bounds__(512, 2) void k6_tconv(const unsigned short* __restrict__ actp,
                                                   const unsigned short* __restrict__ WtT,
                                                   float* __restrict__ y, float* __restrict__ S) {
    __shared__ unsigned short sA[64 * 264];
    __shared__ unsigned short sB[128 * 264];
    const int tid = threadIdx.x;
    const int x = blockIdx.x;
    const int iq = x & 3, pw = (x >> 2) & 1, ph = (x >> 3) & 1, b = x >> 4;
    const int lane = tid & 63, wv = tid >> 6;  // wave = one 16-wide co strip
    f32x4 acc[4];
#pragma unroll
    for (int i = 0; i < 4; ++i) acc[i] = (f32x4){0.f, 0.f, 0.f, 0.f};
    const int kof = (lane >> 4) * 8;
    const int arow = lane & 15;
    const int bco = wv * 16 + (lane & 15);

    for (int a2 = 0; a2 < 2; ++a2)
        for (int c2 = 0; c2 < 2; ++c2) {
            const int kh = ph + 2 * a2, kw = pw + 2 * c2;
            __syncthreads();
            for (int c = tid; c < 2048; c += 512) {   // A: 64 rows x 32 chunks
                int r = c >> 5, k8 = c & 31;
                int i = iq * 4 + (r >> 4), j = r & 15;
                size_t sa = (size_t)((b * 18 + (i + a2 + ph)) * 18 + (j + c2 + pw)) * 256 + k8 * 8;
                *(u16x8*)&sA[r * 264 + k8 * 8] = *(const u16x8*)&actp[sa];
            }
            for (int c = tid; c < 4096; c += 512) {   // B: 128 co x 32 chunks
                int co = c >> 5, k8 = c & 31;
                size_t sb = (size_t)((kh * 4 + kw) * 128 + co) * 256 + k8 * 8;
                *(u16x8*)&sB[co * 264 + k8 * 8] = *(const u16x8*)&WtT[sb];
            }
            __syncthreads();
#pragma unroll
            for (int k8c = 0; k8c < 8; ++k8c) {
                const int ci = k8c * 32 + kof;
                bf16x8 bb = *(const bf16x8*)&sB[bco * 264 + ci];
#pragma unroll
                for (int mf = 0; mf < 4; ++mf) {
                    bf16x8 a = *(const bf16x8*)&sA[(arow + mf * 16) * 264 + ci];
                    acc[mf] = __builtin_amdgcn_mfma_f32_16x16x32_bf16(a, bb, acc[mf], 0, 0, 0);
                }
            }
        }
    float sl = 0.f, ssl = 0.f;
#pragma unroll
    for (int mf = 0; mf < 4; ++mf)
#pragma unroll
        for (int r = 0; r < 4; ++r) {
            float v = acc[mf][r];
            int m = mf * 16 + (lane >> 4) * 4 + r;  // 0..63
            int i = iq * 4 + (m >> 4), j = m & 15;
            int oh = 2 * i + ph, ow = 2 * j + pw;
            y[(size_t)((b * 32 + oh) * 32 + ow) * 128 + bco] = v;
            sl += v; ssl += v * v;
        }
    sl += __shfl_xor(sl, 16); sl += __shfl_xor(sl, 32);
    ssl += __shfl_xor(ssl, 16); ssl += __shfl_xor(ssl, 32);
    if (lane < 16) {
        atomicAdd(&S[1024 + wv * 16 + lane], sl);
        atomicAdd(&S[1152 + wv * 16 + lane], ssl);
    }
}

// K8: out = leaky(BN(y)), f32, params in-block
__global__ __launch_bounds__(256) void k8_out(const float* __restrict__ y,
                                              const float* __restrict__ S,
                                              const float* __restrict__ gt, const float* __restrict__ bt,
                                              float* __restrict__ out) {
    __shared__ float s_p[256];
    if (threadIdx.x < 128) {
        int c = threadIdx.x;
        const float inv_n = 1.f / 8192.f;
        float mean = S[1024 + c] * inv_n;
        float var = S[1152 + c] * inv_n - mean * mean;
        float sc = gt[c] * rsqrtf(var + 1e-3f);
        s_p[c] = sc;
        s_p[128 + c] = bt[c] - mean * sc;
    }
    __syncthreads();
    int c = blockIdx.x * 256 + threadIdx.x;  // < 262,144
    const float4 v = *(const float4*)&y[(size_t)c * 4];
    int cb = (c & 31) * 4;
    float4 o;
    o.x = lrelu(s_p[cb + 0] * v.x + s_p[128 + cb + 0]);
    o.y = lrelu(s_p[cb + 1] * v.y + s_p[128 + cb + 1]);
    o.z = lrelu(s_p[cb + 2] * v.z + s_p[128 + cb + 2]);
    o.w = lrelu(s_p[cb + 3] * v.w + s_p[128 + cb + 3]);
    *(float4*)&out[(size_t)c * 4] = o;
}

extern "C" void kernel_launch(void* const* d_in, const int* in_sizes, int n_in,
                              void* d_out, int out_size, void* d_ws, size_t ws_size,
                              hipStream_t stream) {
    (void)in_sizes; (void)n_in; (void)out_size; (void)ws_size;
    const float* X    = (const float*)d_in[0];
    const float* Wq   = (const float*)d_in[1];
    const float* gq   = (const float*)d_in[2];
    const float* bq   = (const float*)d_in[3];
    const float* Wk   = (const float*)d_in[4];
    const float* gk   = (const float*)d_in[5];
    const float* bk   = (const float*)d_in[6];
    const float* beta = (const float*)d_in[7];
    const float* g1   = (const float*)d_in[8];
    const float* b1   = (const float*)d_in[9];
    const float* Wt   = (const float*)d_in[10];
    const float* gt   = (const float*)d_in[11];
    const float* bt   = (const float*)d_in[12];

    char* ws = (char*)d_ws;
    unsigned short* Qraw = (unsigned short*)(ws + 0ull);
    unsigned short* Kraw = (unsigned short*)(ws + 33554432ull);
    unsigned short* WqT  = (unsigned short*)(ws + 67108864ull);
    unsigned short* WkT  = (unsigned short*)(ws + 67403776ull);
    unsigned short* WtT  = (unsigned short*)(ws + 67698688ull);
    float* S             = (float*)(ws + 68747264ull);
    unsigned short* Xb   = (unsigned short*)(ws + 68761600ull);
    float* part          = (float*)(ws + 68761600ull);   // overlays dead Xb
    float* sim           = (float*)(ws + 0ull);          // overlays dead Qraw
    unsigned short* actp = (unsigned short*)(ws + 4194304ull);
    float* y             = (float*)(ws + 8388608ull);
    float* out           = (float*)d_out;

    k0a_prep<<<1024, 256, 0, stream>>>(Wq, Wk, Wt, WqT, WkT, WtT, S);
    k0b_padx<<<8450, 256, 0, stream>>>(X, Xb);
    k1_conv<<<1024, 512, 0, stream>>>(Xb, WqT, WkT, Qraw, Kraw, S);
    k3_sim<<<256, 512, 0, stream>>>(Qraw, Kraw, S, gq, bq, gk, bk, part);
    k4_red<<<256, 256, 0, stream>>>(part, beta, sim, S);
    k5b_act<<<729, 256, 0, stream>>>(sim, S, g1, b1, actp);
    k6_tconv<<<128, 512, 0, stream>>>(actp, WtT, y, S);
    k8_out<<<1024, 256, 0, stream>>>(y, S, gt, bt, out);
}